// Round 14
// baseline (83.745 us; speedup 1.0000x reference)
//
#include <hip/hip_runtime.h>
#include <hip/hip_fp16.h>
#include <math.h>

// Problem constants
#define NSIG 64          // 2 inputs x 32 batch
#define NROW 192000      // input row length
#define NN   192000      // irfft length
#define LP   192512      // padded time length (multiple of HOP)
#define NT   93          // STFT frames
#define NF   2049        // rfft bins of 4096
#define PSTR 2050        // padded P row stride (halfs) -> half2-aligned
#define PTS  (NT*PSTR)   // P elems per row = 190650
#define NK2  188         // stored k2 rows (A[375-k2] = conj(A[k2]))
#define TWO_PI 6.28318530717958647692f
#define SQ2H  0.70710678118654752440f
#define DB_LOG2 3.01029995663981195f   // 10/log2(10)

// Workspace layout (bytes):
//   P : [0, 24403200)               64*93*2050 half  (|S| magnitudes)
//   A : [24403200, +24641536)       64*188*512 half2 [sig][k2][i] (conj-sym half rows)
//   Y : [49044736, +24641536)       64*192512 half
//   ACC: [73686272, +256)           32*2 float accumulators
#define WS_P_OFF   0
#define WS_A_OFF   24403200ULL
#define WS_Y_OFF   49044736ULL
#define WS_ACC_OFF 73686272ULL

__device__ __forceinline__ float2 cmul(float2 a, float2 b) {
    return make_float2(a.x*b.x - a.y*b.y, a.x*b.y + a.y*b.x);
}
__device__ __forceinline__ float2 cadd(float2 a, float2 b) {
    return make_float2(a.x + b.x, a.y + b.y);
}
__device__ __forceinline__ float2 csub(float2 a, float2 b) {
    return make_float2(a.x - b.x, a.y - b.y);
}
__device__ __forceinline__ float2 mul_nI(float2 z) { return make_float2(z.y, -z.x); }   // z * -i
__device__ __forceinline__ float2 mul_pI(float2 z) { return make_float2(-z.y, z.x); }   // z * +i
__device__ __forceinline__ __half2 f2h(float2 v) { return __float22half2_rn(v); }
__device__ __forceinline__ float2 h2f(__half2 h) { return __half22float2(h); }

// 8-point DFT, forward sign (e^{-2pi i rk/8}) — used by k_stft.
__device__ __forceinline__ void dft8(float2 (&x)[8]) {
    float2 e0 = cadd(x[0], x[4]), e1 = csub(x[0], x[4]);
    float2 e2 = cadd(x[2], x[6]), e3 = csub(x[2], x[6]);
    float2 E0 = cadd(e0, e2), E2 = csub(e0, e2);
    float2 E1 = cadd(e1, mul_nI(e3)), E3 = csub(e1, mul_nI(e3));
    float2 o0 = cadd(x[1], x[5]), o1 = csub(x[1], x[5]);
    float2 o2 = cadd(x[3], x[7]), o3 = csub(x[3], x[7]);
    float2 O0 = cadd(o0, o2), O2 = csub(o0, o2);
    float2 O1 = cadd(o1, mul_nI(o3)), O3 = csub(o1, mul_nI(o3));
    float2 W1 = make_float2(SQ2H*(O1.x + O1.y), SQ2H*(O1.y - O1.x));
    float2 W2 = mul_nI(O2);
    float2 W3 = make_float2(SQ2H*(O3.y - O3.x), -SQ2H*(O3.x + O3.y));
    x[0] = cadd(E0, O0); x[4] = csub(E0, O0);
    x[1] = cadd(E1, W1); x[5] = csub(E1, W1);
    x[2] = cadd(E2, W2); x[6] = csub(E2, W2);
    x[3] = cadd(E3, W3); x[7] = csub(E3, W3);
}

// 8-point DFT, inverse sign (e^{+2pi i rk/8}).
__device__ __forceinline__ void dft8i(float2 (&x)[8]) {
    float2 e0 = cadd(x[0], x[4]), e1 = csub(x[0], x[4]);
    float2 e2 = cadd(x[2], x[6]), e3 = csub(x[2], x[6]);
    float2 E0 = cadd(e0, e2), E2 = csub(e0, e2);
    float2 E1 = cadd(e1, mul_pI(e3)), E3 = csub(e1, mul_pI(e3));
    float2 o0 = cadd(x[1], x[5]), o1 = csub(x[1], x[5]);
    float2 o2 = cadd(x[3], x[7]), o3 = csub(x[3], x[7]);
    float2 O0 = cadd(o0, o2), O2 = csub(o0, o2);
    float2 O1 = cadd(o1, mul_pI(o3)), O3 = csub(o1, mul_pI(o3));
    float2 W1 = make_float2(SQ2H*(O1.x - O1.y), SQ2H*(O1.x + O1.y));   // *e^{+i pi/4}
    float2 W2 = mul_pI(O2);
    float2 W3 = make_float2(-SQ2H*(O3.x + O3.y), SQ2H*(O3.x - O3.y));  // *e^{+3i pi/4}
    x[0] = cadd(E0, O0); x[4] = csub(E0, O0);
    x[1] = cadd(E1, W1); x[5] = csub(E1, W1);
    x[2] = cadd(E2, W2); x[6] = csub(E2, W2);
    x[3] = cadd(E3, W3); x[7] = csub(E3, W3);
}

// 3-point DFT, inverse sign.
#define S3C 0.86602540378443865f
__device__ __forceinline__ void dft3i(float2& x0, float2& x1, float2& x2) {
    float2 u = cadd(x1, x2), v = csub(x1, x2);
    float2 w = make_float2(x0.x - 0.5f*u.x, x0.y - 0.5f*u.y);
    x0 = cadd(x0, u);
    float2 iv = make_float2(-S3C * v.y, S3C * v.x);
    x1 = cadd(w, iv);
    x2 = csub(w, iv);
}

// 5-point DFT, inverse sign.
#define C51 0.30901699437494742f
#define S51 0.95105651629515357f
#define C52 (-0.80901699437494742f)
#define S52 0.58778525229247313f
__device__ __forceinline__ void dft5i(float2& x0, float2& x1, float2& x2,
                                      float2& x3, float2& x4) {
    float2 t1 = cadd(x1, x4), t2 = csub(x1, x4);
    float2 t3 = cadd(x2, x3), t4 = csub(x2, x3);
    float2 s0 = x0;
    x0 = make_float2(s0.x + t1.x + t3.x, s0.y + t1.y + t3.y);
    float2 A1 = make_float2(s0.x + C51*t1.x + C52*t3.x, s0.y + C51*t1.y + C52*t3.y);
    float2 B1 = make_float2(S51*t2.x + S52*t4.x, S51*t2.y + S52*t4.y);
    float2 A2 = make_float2(s0.x + C52*t1.x + C51*t3.x, s0.y + C52*t1.y + C51*t3.y);
    float2 B2 = make_float2(S52*t2.x - S51*t4.x, S52*t2.y - S51*t4.y);
    x1 = make_float2(A1.x - B1.y, A1.y + B1.x);
    x4 = make_float2(A1.x + B1.y, A1.y - B1.x);
    x2 = make_float2(A2.x - B2.y, A2.y + B2.x);
    x3 = make_float2(A2.x + B2.y, A2.y - B2.x);
}

// Stage 1: 8 k2 rows per block = 4 complex FFT-512 (real-pair packing), ONE
// FFT per wave. Waves are fully independent (private LDS strips) -> no block
// barriers at all, only wave_barriers. Grid 1536 = 24 chunks x 64 sigs
// (6 blocks/CU vs 3 before). Only k2 < 188 stored: A[375-k2] = conj(A[k2]).
#define SSTR 520   // strip stride (floats); 520 % 32 == 8
__global__ void __launch_bounds__(256) k_stage1(const float* __restrict__ X0,
                                                const float* __restrict__ X1,
                                                __half2* __restrict__ A) {
    const int bid  = blockIdx.x;       // [0,1536)
    const int sig  = bid & 63;
    const int kb   = bid >> 6;         // [0,24)
    const int base = kb * 8;
    const float* X = (sig < 32) ? (X0 + (size_t)sig * NROW)
                                : (X1 + (size_t)(sig - 32) * NROW);
    __shared__ float SR[4 * SSTR], SI[4 * SSTR];   // 16640 B total
    const int tid = threadIdx.x;
    const int w   = tid >> 6;          // wave id = complex row
    const int l   = tid & 63;          // lane

    const int k2e0 = base + 2 * w;     // may reach 190 (kb=23): guarded below
    const int k2e  = (k2e0 < NK2) ? k2e0 : (NK2 - 1);
    const int k2o  = (k2e0 + 1 < NK2) ? (k2e0 + 1) : (NK2 - 1);

    float* srw = SR + SSTR * w;
    float* siw = SI + SSTR * w;

    // ---- staging (wave-private): z[n] = (X[375n+k2e], X[375n+k2o]), n = l + 64m
    #pragma unroll
    for (int m = 0; m < 8; ++m) {
        int i = l + 64 * m;
        int ide = 375 * i + k2e;
        int ido = 375 * i + k2o;
        srw[i] = X[(ide <= 96000) ? ide : (NN - ide)];
        siw[i] = X[(ido <= 96000) ? ido : (NN - ido)];
    }
    __builtin_amdgcn_wave_barrier();

    float2 x[8];

    // phase A: x[n1] = z[l + 64 n1]; dft8 over n1; twiddle W512^{+l*a}
    #pragma unroll
    for (int n1 = 0; n1 < 8; ++n1) {
        int ad = l + 64 * n1;
        x[n1] = make_float2(srw[ad], siw[ad]);
    }
    dft8i(x);
    {
        float sn, cs; __sincosf(TWO_PI * (float)l * (1.0f / 512.0f), &sn, &cs);
        float2 bw = make_float2(cs, sn), tw = bw;
        x[1] = cmul(x[1], tw);
        #pragma unroll
        for (int k = 2; k < 8; ++k) { tw = cmul(tw, bw); x[k] = cmul(x[k], tw); }
    }
    // exchange 1 write: addr = 64a + (l ^ 8a)  (<=2-way per wave)
    #pragma unroll
    for (int a2 = 0; a2 < 8; ++a2) {
        int ad = 64 * a2 + (l ^ (8 * a2));
        srw[ad] = x[a2].x; siw[ad] = x[a2].y;
    }
    __builtin_amdgcn_wave_barrier();

    // phase B: lane = (l0 = l&7, aa = l>>3); y[l1] = T_A[l0+8l1][aa]
    const int l0 = l & 7, aa = l >> 3;
    #pragma unroll
    for (int l1 = 0; l1 < 8; ++l1) {
        int ad = 64 * aa + ((l0 + 8 * l1) ^ (8 * aa));
        x[l1] = make_float2(srw[ad], siw[ad]);
    }
    dft8i(x);
    {
        float sn, cs; __sincosf(TWO_PI * (float)l0 * (1.0f / 64.0f), &sn, &cs);
        float2 bw = make_float2(cs, sn), tw = bw;
        x[1] = cmul(x[1], tw);
        #pragma unroll
        for (int k = 2; k < 8; ++k) { tw = cmul(tw, bw); x[k] = cmul(x[k], tw); }
    }
    // exchange 2 write: addr = 64b + 8aa + (l0 ^ b)
    #pragma unroll
    for (int b2 = 0; b2 < 8; ++b2) {
        int ad = 64 * b2 + 8 * aa + (l0 ^ b2);
        srw[ad] = x[b2].x; siw[ad] = x[b2].y;
    }
    __builtin_amdgcn_wave_barrier();

    // phase C: lane = (a3 = l&7, b3 = l>>3); w[l0] = T_B[l0][a3][b3]
    const int a3 = l & 7, b3 = l >> 3;
    #pragma unroll
    for (int l0r = 0; l0r < 8; ++l0r) {
        int ad = 64 * b3 + 8 * a3 + (l0r ^ b3);
        x[l0r] = make_float2(srw[ad], siw[ad]);
    }
    dft8i(x);
    // Z[a3 + 8 b3 + 64 c] — natural order for the epilogue
    #pragma unroll
    for (int c = 0; c < 8; ++c) {
        int ad = a3 + 8 * b3 + 64 * c;
        srw[ad] = x[c].x; siw[ad] = x[c].y;
    }
    __builtin_amdgcn_wave_barrier();

    // ---- Hermitian unpack + twiddle W_N^{+k2 i} (chained) + coalesced half2 store
    if (k2e0 < NK2) {
        float sn, cs;
        __sincosf(TWO_PI * (float)(k2e * l) * (1.0f / 192000.0f), &sn, &cs);
        float2 wke = make_float2(cs, sn);
        __sincosf(TWO_PI * (float)(64 * k2e) * (1.0f / 192000.0f), &sn, &cs);
        float2 ste = make_float2(cs, sn);
        __sincosf(TWO_PI * (float)(k2o * l) * (1.0f / 192000.0f), &sn, &cs);
        float2 wko = make_float2(cs, sn);
        __sincosf(TWO_PI * (float)(64 * k2o) * (1.0f / 192000.0f), &sn, &cs);
        float2 sto = make_float2(cs, sn);
        const bool odd_ok = (k2e0 + 1 < NK2);
        __half2* Ae = A + ((size_t)sig * NK2 + k2e) * 512;
        __half2* Ao = A + ((size_t)sig * NK2 + k2o) * 512;
        #pragma unroll
        for (int m = 0; m < 8; ++m) {
            int k  = l + 64 * m;
            int km = (512 - k) & 511;
            float2 Z  = make_float2(srw[k],  siw[k]);
            float2 Zm = make_float2(srw[km], siw[km]);
            float2 S = make_float2(Z.x + Zm.x, Z.y - Zm.y);    // Z + conj(Zm)
            float2 D = make_float2(Z.x - Zm.x, Z.y + Zm.y);    // Z - conj(Zm)
            float2 Xe = make_float2(0.5f * S.x, 0.5f * S.y);
            float2 Xo = make_float2(0.5f * D.y, -0.5f * D.x);  // D/(2i)
            Ae[k] = f2h(cmul(Xe, wke));
            if (odd_ok) Ao[k] = f2h(cmul(Xo, wko));
            wke = cmul(wke, ste);
            wko = cmul(wko, sto);
        }
    }
}

// Stage 2: block = (t1 tile of 32 = 16 PAIRS, sig). Two-for-one real-output
// IDFT-375: z[k2] = A[k2][t1a] + i*A[k2][t1a+1] (A column conj-symmetric =>
// each output real) -> one complex DFT yields y_a = Re, y_b = Im.
// Rows k2 >= 188 synthesized from conj symmetry. Grid (16, 64).
#define TP2 16     // pairs per block (32 t1)
#define T1STR 17
__global__ void __launch_bounds__(256) k_stage2(const __half2* __restrict__ A,
                                                __half* __restrict__ Y) {
    const int t1b = blockIdx.x * (2 * TP2);   // first t1 of tile (even)
    const int sig = blockIdx.y;
    __shared__ float SRT[375 * T1STR], SIT[375 * T1STR];  // 51000 B
    const int tid = threadIdx.x;

    if (blockIdx.x == 0) {             // zero pad tail Y[sig][192000:192512)
        for (int j = tid; j < 512; j += 256)
            Y[(size_t)sig * LP + NN + j] = __float2half(0.f);
    }

    // Phase A: per (c<25, pair): DFT-15 over a (k2 = 25a + c) + twiddle W375^{ce}
    for (int w = tid; w < 25 * TP2; w += 256) {
        int c = w >> 4, pl = w & 15;            // pair lane
        float2 v[15];
        const float2* Asf = (const float2*)(A + (size_t)sig * (NK2 * 512) + t1b + 2 * pl);
        #pragma unroll
        for (int a = 0; a < 15; ++a) {
            int k2 = 25 * a + c;
            if (k2 < NK2) {
                float2 raw = Asf[(size_t)k2 * 256];
                float2 fa = h2f(((const __half2*)&raw)[0]);
                float2 fb = h2f(((const __half2*)&raw)[1]);
                v[a] = make_float2(fa.x - fb.y, fa.y + fb.x);       // A_a + i A_b
            } else {
                float2 raw = Asf[(size_t)(375 - k2) * 256];
                float2 fa = h2f(((const __half2*)&raw)[0]);
                float2 fb = h2f(((const __half2*)&raw)[1]);
                v[a] = make_float2(fa.x + fb.y, fb.x - fa.y);       // conj(u_a)+i conj(u_b)
            }
        }
        #pragma unroll
        for (int r = 0; r < 5; ++r) dft3i(v[r], v[r + 5], v[r + 10]);
        float2 tw[15];
        tw[0] = make_float2(1.f, 0.f);
        float sn, cs; __sincosf(TWO_PI * (float)c * (1.0f / 375.0f), &sn, &cs);
        float2 stp = make_float2(cs, sn);
        #pragma unroll
        for (int e = 1; e < 15; ++e) tw[e] = cmul(tw[e - 1], stp);
        #pragma unroll
        for (int e3 = 0; e3 < 3; ++e3) {
            float2 h0 = v[5 * e3], h1, h2, h3, h4;
            if (e3 == 0) { h1 = v[1]; h2 = v[2]; h3 = v[3]; h4 = v[4]; }
            else if (e3 == 1) {
                h1 = cmul(v[6],  make_float2(0.91354545764260090f, 0.40673664307580021f));   // W15^1
                h2 = cmul(v[7],  make_float2(0.66913060635885821f, 0.74314482547739424f));   // W15^2
                h3 = cmul(v[8],  make_float2(0.30901699437494742f, 0.95105651629515357f));   // W15^3
                h4 = cmul(v[9],  make_float2(-0.10452846326765347f, 0.99452189536827334f));  // W15^4
            } else {
                h1 = cmul(v[11], make_float2(0.66913060635885821f, 0.74314482547739424f));   // W15^2
                h2 = cmul(v[12], make_float2(-0.10452846326765347f, 0.99452189536827334f));  // W15^4
                h3 = cmul(v[13], make_float2(-0.80901699437494742f, 0.58778525229247313f));  // W15^6
                h4 = cmul(v[14], make_float2(-0.97814760073380564f, -0.20791169081775934f)); // W15^8
            }
            dft5i(h0, h1, h2, h3, h4);
            float2 o0 = cmul(h0, tw[e3]);
            float2 o1 = cmul(h1, tw[e3 + 3]);
            float2 o2 = cmul(h2, tw[e3 + 6]);
            float2 o3 = cmul(h3, tw[e3 + 9]);
            float2 o4 = cmul(h4, tw[e3 + 12]);
            int r0 = ((e3     ) * 25 + c) * T1STR + pl;
            int r1 = ((e3 + 3 ) * 25 + c) * T1STR + pl;
            int r2 = ((e3 + 6 ) * 25 + c) * T1STR + pl;
            int r3 = ((e3 + 9 ) * 25 + c) * T1STR + pl;
            int r4 = ((e3 + 12) * 25 + c) * T1STR + pl;
            SRT[r0] = o0.x; SIT[r0] = o0.y;
            SRT[r1] = o1.x; SIT[r1] = o1.y;
            SRT[r2] = o2.x; SIT[r2] = o2.y;
            SRT[r3] = o3.x; SIT[r3] = o3.y;
            SRT[r4] = o4.x; SIT[r4] = o4.y;
        }
    }
    __syncthreads();

    // Phase B: per (e<15, pair): DFT-25 over c = 5*c1 + c2, all-constant twiddles
    if (tid < 15 * TP2) {
        int e = tid >> 4, pl = tid & 15;
        float2 t[25];
        #pragma unroll
        for (int c = 0; c < 25; ++c) {
            int rr = (e * 25 + c) * T1STR + pl;
            t[c] = make_float2(SRT[rr], SIT[rr]);
        }
        #pragma unroll
        for (int c2 = 0; c2 < 5; ++c2)
            dft5i(t[c2], t[c2 + 5], t[c2 + 10], t[c2 + 15], t[c2 + 20]);
        t[6]  = cmul(t[6],  make_float2(0.96858316112863108f, 0.24868988716485479f));   // W25^1
        t[11] = cmul(t[11], make_float2(0.87630668004386358f, 0.48175367410171532f));   // W25^2
        t[16] = cmul(t[16], make_float2(0.72896862742141155f, 0.68454710592868873f));   // W25^3
        t[21] = cmul(t[21], make_float2(0.53582679497899666f, 0.84432792550201508f));   // W25^4
        t[7]  = cmul(t[7],  make_float2(0.87630668004386358f, 0.48175367410171532f));   // W25^2
        t[12] = cmul(t[12], make_float2(0.53582679497899666f, 0.84432792550201508f));   // W25^4
        t[17] = cmul(t[17], make_float2(0.06279051952931337f, 0.99802672842827156f));   // W25^6
        t[22] = cmul(t[22], make_float2(-0.42577929156507272f, 0.90482705246601958f));  // W25^8
        t[8]  = cmul(t[8],  make_float2(0.72896862742141155f, 0.68454710592868873f));   // W25^3
        t[13] = cmul(t[13], make_float2(0.06279051952931337f, 0.99802672842827156f));   // W25^6
        t[18] = cmul(t[18], make_float2(-0.63742398974868975f, 0.77051324277578925f));  // W25^9
        t[23] = cmul(t[23], make_float2(-0.99211470131447788f, 0.12533323356430426f));  // W25^12
        t[9]  = cmul(t[9],  make_float2(0.53582679497899666f, 0.84432792550201508f));   // W25^4
        t[14] = cmul(t[14], make_float2(-0.42577929156507272f, 0.90482705246601958f));  // W25^8
        t[19] = cmul(t[19], make_float2(-0.99211470131447788f, 0.12533323356430426f));  // W25^12
        t[24] = cmul(t[24], make_float2(-0.63742398974868997f, -0.77051324277578903f)); // W25^16
        #pragma unroll
        for (int u5 = 0; u5 < 5; ++u5)
            dft5i(t[5*u5], t[5*u5 + 1], t[5*u5 + 2], t[5*u5 + 3], t[5*u5 + 4]);
        // w[t2] -> y_a = Re, y_b = Im; paired half2 store at (t1a, t1a+1)
        __half2* yb2 = (__half2*)(Y + (size_t)sig * LP + t1b + 2 * pl);
        #pragma unroll
        for (int u5 = 0; u5 < 5; ++u5)
            #pragma unroll
            for (int u5p = 0; u5p < 5; ++u5p) {
                int d = u5 + 5 * u5p;          // t2 = 15*d + e
                float2 wv = t[5 * u5 + u5p];
                yb2[(size_t)256 * (15 * d + e)] =
                    __floats2half2_rn(wv.x * (1.0f / 192000.0f),
                                      wv.y * (1.0f / 192000.0f));
            }
    }
}

// STFT: real-packed FFT-2048 in registers (radix 8,8,8,4), 3 LDS exchanges,
// Hermitian unpack; stores |S| as half (P stride 2050). 1D grid 5952,
// sig = bid&63 -> same-signal frames share one XCD L2 (window overlap reuse).
__global__ void __launch_bounds__(256) k_stft(const __half* __restrict__ Y,
                                              __half* __restrict__ P,
                                              float* __restrict__ ACC) {
    const int bid = blockIdx.x;
    const int sig = bid & 63;     // [0,64)
    const int fr  = bid >> 6;     // [0,93)
    const int lt  = threadIdx.x;  // [0,256)
    __shared__ float SR[2560], SI[2560];
    __shared__ float2 wt2[32];
    float2 x[8];
    float2 base2048;              // e^{+i*2pi*lt/2048}

    if (bid == 0 && lt < 64) ACC[lt] = 0.f;   // zero loss accumulators

    {
        const __half2* yb = (const __half2*)(Y + (size_t)sig * LP + (size_t)fr * 2048);
        float sn, cs;
        __sincosf(TWO_PI * (float)lt * (1.0f / 2048.0f), &sn, &cs);
        base2048 = make_float2(cs, sn);
        float2 ce = base2048;
        const float2 d1 = make_float2(0.99999882345170188f,   // e^{+i*pi/2048}
                                      0.00153398018628477f);
        float2 co = cmul(ce, d1);
        const float2 r45 = make_float2(SQ2H, SQ2H);
        #pragma unroll
        for (int r = 0; r < 8; ++r) {
            float2 v = h2f(yb[lt + 256 * r]);
            float we = 0.5f - 0.5f * ce.x;
            float wo = 0.5f - 0.5f * co.x;
            x[r] = make_float2(v.x * we, v.y * wo);
            ce = cmul(ce, r45);
            co = cmul(co, r45);
        }
    }
    dft8(x);
    {
        float2 b = make_float2(base2048.x, -base2048.y), tw = b;  // conj
        x[1] = cmul(x[1], tw);
        #pragma unroll
        for (int k = 2; k < 8; ++k) { tw = cmul(tw, b); x[k] = cmul(x[k], tw); }
    }
    #pragma unroll
    for (int k = 0; k < 8; ++k) { SR[k * 256 + lt] = x[k].x; SI[k * 256 + lt] = x[k].y; }
    if (lt < 32) {
        float sn, cs; __sincosf(-TWO_PI * (float)lt * (1.0f / 256.0f), &sn, &cs);
        wt2[lt] = make_float2(cs, sn);
    }
    __syncthreads();

    {
        const int k2 = lt >> 5, m1 = lt & 31;
        #pragma unroll
        for (int r = 0; r < 8; ++r) {
            int idx = k2 * 256 + m1 + 32 * r;
            x[r] = make_float2(SR[idx], SI[idx]);
        }
        dft8(x);
        float2 b = wt2[m1], tw = b;
        x[1] = cmul(x[1], tw);
        #pragma unroll
        for (int k = 2; k < 8; ++k) { tw = cmul(tw, b); x[k] = cmul(x[k], tw); }
        __syncthreads();
        #pragma unroll
        for (int j = 0; j < 8; ++j) {
            int idx = k2 * 288 + j * 36 + m1;
            SR[idx] = x[j].x; SI[idx] = x[j].y;
        }
    }
    __syncthreads();

    {
        const int k2 = lt >> 5, j2 = (lt >> 2) & 7, p1 = lt & 3;
        #pragma unroll
        for (int r = 0; r < 8; ++r) {
            int idx = k2 * 288 + j2 * 36 + p1 + 4 * r;
            x[r] = make_float2(SR[idx], SI[idx]);
        }
        dft8(x);
        float2 b = (p1 == 0) ? make_float2(1.f, 0.f)
                 : (p1 == 1) ? make_float2(0.98078528040323044f, -0.19509032201612827f)
                 : (p1 == 2) ? make_float2(0.92387953251128676f, -0.38268343236508977f)
                 :             make_float2(0.83146961230254524f, -0.55557023301960222f);
        float2 tw = b;
        x[1] = cmul(x[1], tw);
        #pragma unroll
        for (int k = 2; k < 8; ++k) { tw = cmul(tw, b); x[k] = cmul(x[k], tw); }
        __syncthreads();
        #pragma unroll
        for (int q = 0; q < 8; ++q) {
            int idx = 5 * (q * 64 + k2 * 8 + j2) + p1;
            SR[idx] = x[q].x; SI[idx] = x[q].y;
        }
    }
    __syncthreads();

    {
        float2 za[4], zb[4];
        #pragma unroll
        for (int p = 0; p < 4; ++p) {
            int ia = 5 * lt + p;
            za[p] = make_float2(SR[ia], SI[ia]);
            zb[p] = make_float2(SR[ia + 1280], SI[ia + 1280]);
        }
        __syncthreads();
        const int q2a = lt >> 6, k2 = (lt >> 3) & 7, j2 = lt & 7;
        const int kbase = k2 + 8 * j2;
        {
            float2 s0 = cadd(za[0], za[2]), s1 = csub(za[0], za[2]);
            float2 s2 = cadd(za[1], za[3]), s3 = csub(za[1], za[3]);
            float2 X0 = cadd(s0, s2), X2 = csub(s0, s2);
            float2 X1 = cadd(s1, mul_nI(s3)), X3 = csub(s1, mul_nI(s3));
            int ka = kbase + 64 * q2a;
            SR[ka]        = X0.x; SI[ka]        = X0.y;
            SR[ka + 512]  = X1.x; SI[ka + 512]  = X1.y;
            SR[ka + 1024] = X2.x; SI[ka + 1024] = X2.y;
            SR[ka + 1536] = X3.x; SI[ka + 1536] = X3.y;
        }
        {
            float2 s0 = cadd(zb[0], zb[2]), s1 = csub(zb[0], zb[2]);
            float2 s2 = cadd(zb[1], zb[3]), s3 = csub(zb[1], zb[3]);
            float2 X0 = cadd(s0, s2), X2 = csub(s0, s2);
            float2 X1 = cadd(s1, mul_nI(s3)), X3 = csub(s1, mul_nI(s3));
            int kb = kbase + 64 * (q2a + 4);
            SR[kb]        = X0.x; SI[kb]        = X0.y;
            SR[kb + 512]  = X1.x; SI[kb + 512]  = X1.y;
            SR[kb + 1024] = X2.x; SI[kb + 1024] = X2.y;
            SR[kb + 1536] = X3.x; SI[kb + 1536] = X3.y;
        }
    }
    __syncthreads();

    {
        __half* pb = P + (size_t)sig * PTS + (size_t)fr * PSTR;
        // wk = e^{-i*2pi*lt/4096} via half-angle of base2048 (lt<256 -> theta<0.79)
        float c2 = sqrtf(0.5f * (1.f + base2048.x));
        float s2 = sqrtf(0.5f * (1.f - base2048.x));
        float2 wk = make_float2(c2, -s2);
        const float2 stp = make_float2(0.92387953251128676f,   // e^{-i*pi/8}
                                       -0.38268343236508977f);
        #pragma unroll
        for (int j = 0; j < 8; ++j) {
            int k  = lt + 256 * j;
            int kc = (2048 - k) & 2047;
            float zr = SR[k],  zi = SI[k];
            float cr = SR[kc], ci = SI[kc];
            float Ex = 0.5f * (zr + cr), Ey = 0.5f * (zi - ci);
            float Ox = 0.5f * (zi + ci), Oy = -0.5f * (zr - cr);
            float Xx = Ex + wk.x * Ox - wk.y * Oy;
            float Xy = Ey + wk.x * Oy + wk.y * Ox;
            pb[k] = __float2half_rn(sqrtf(Xx * Xx + Xy * Xy));   // store |S|
            wk = cmul(wk, stp);
        }
        if (lt == 0) { float d0 = SR[0] - SI[0]; pb[2048] = __float2half_rn(fabsf(d0)); }
    }
}

// EDR + loss partials. P holds |S| as half; square on load.
// 1 bin per thread, grid (9,32); dB via hardware v_log_f32.
__global__ void __launch_bounds__(256) k_edr(const __half* __restrict__ P,
                                             float* __restrict__ ACC) {
    const int b = blockIdx.y;
    const int f = blockIdx.x * 256 + threadIdx.x;
    const bool act = (f < NF);
    const __half* Pt = P + (size_t)b * PTS;
    const __half* Pa = P + (size_t)(b + 32) * PTS;
    float st = 0.f, sa = 0.f, num = 0.f, den = 0.f;
    if (act) {
        for (int t = NT - 1; t >= 0; --t) {
            float vt = __half2float(Pt[(size_t)t * PSTR + f]);
            float va = __half2float(Pa[(size_t)t * PSTR + f]);
            st += vt * vt;
            sa += va * va;
            float et = DB_LOG2 * __log2f(st);
            float ea = DB_LOG2 * __log2f(sa);
            num += fabsf(et - ea);
            den += fabsf(et);
        }
    }
    for (int off = 32; off > 0; off >>= 1) {
        num += __shfl_down(num, off);
        den += __shfl_down(den, off);
    }
    __shared__ float sn_[4], sd_[4];
    int wave = threadIdx.x >> 6, lane = threadIdx.x & 63;
    if (lane == 0) { sn_[wave] = num; sd_[wave] = den; }
    __syncthreads();
    if (threadIdx.x == 0) {
        float n = sn_[0] + sn_[1] + sn_[2] + sn_[3];
        float d = sd_[0] + sd_[1] + sd_[2] + sd_[3];
        atomicAdd(&ACC[2 * b], n);
        atomicAdd(&ACC[2 * b + 1], d);
    }
}

__global__ void k_final(const float* __restrict__ ACC, float* __restrict__ out) {
    int tid = threadIdx.x;
    float r = 0.f;
    if (tid < 32) r = ACC[2 * tid] / ACC[2 * tid + 1];
    for (int off = 32; off > 0; off >>= 1) r += __shfl_down(r, off);
    if (tid == 0) out[0] = r;
}

extern "C" void kernel_launch(void* const* d_in, const int* in_sizes, int n_in,
                              void* d_out, int out_size, void* d_ws, size_t ws_size,
                              hipStream_t stream) {
    const float* X0 = (const float*)d_in[0];
    const float* X1 = (const float*)d_in[1];
    float* out = (float*)d_out;

    char* base = (char*)d_ws;
    __half*  P  = (__half*)(base + WS_P_OFF);
    __half2* A  = (__half2*)(base + WS_A_OFF);
    __half*  Y  = (__half*)(base + WS_Y_OFF);
    float*   ACC = (float*)(base + WS_ACC_OFF);

    k_stage1<<<dim3(1536),     dim3(256), 0, stream>>>(X0, X1, A);
    k_stage2<<<dim3(16, 64),   dim3(256), 0, stream>>>(A, Y);
    k_stft  <<<dim3(5952),     dim3(256), 0, stream>>>(Y, P, ACC);
    k_edr   <<<dim3(9, 32),    dim3(256), 0, stream>>>(P, ACC);
    k_final <<<1, 64, 0, stream>>>(ACC, out);
}

// Round 15
// 79.080 us; speedup vs baseline: 1.0590x; 1.0590x over previous
//
#include <hip/hip_runtime.h>
#include <hip/hip_fp16.h>
#include <math.h>

// Problem constants
#define NSIG 64          // 2 inputs x 32 batch
#define NROW 192000      // input row length
#define NN   192000      // irfft length
#define LP   192512      // padded time length (multiple of HOP)
#define NT   93          // STFT frames
#define NF   2049        // rfft bins of 4096
#define PSTR 2050        // padded P row stride (halfs) -> half2-aligned
#define PTS  (NT*PSTR)   // P elems per row = 190650
#define NK2  188         // stored k2 rows (A[375-k2] = conj(A[k2]))
#define TWO_PI 6.28318530717958647692f
#define SQ2H  0.70710678118654752440f
#define DB_LOG2 3.01029995663981195f   // 10/log2(10)

// Workspace layout (bytes):
//   P : [0, 24403200)               64*93*2050 half  (|S| magnitudes)
//   A : [24403200, +24641536)       64*188*512 half2 [sig][k2][i] (conj-sym half rows)
//   Y : [49044736, +24641536)       64*192512 half
//   ACC: [73686272, +256)           32*2 float accumulators
#define WS_P_OFF   0
#define WS_A_OFF   24403200ULL
#define WS_Y_OFF   49044736ULL
#define WS_ACC_OFF 73686272ULL

__device__ __forceinline__ float2 cmul(float2 a, float2 b) {
    return make_float2(a.x*b.x - a.y*b.y, a.x*b.y + a.y*b.x);
}
__device__ __forceinline__ float2 cadd(float2 a, float2 b) {
    return make_float2(a.x + b.x, a.y + b.y);
}
__device__ __forceinline__ float2 csub(float2 a, float2 b) {
    return make_float2(a.x - b.x, a.y - b.y);
}
__device__ __forceinline__ float2 mul_nI(float2 z) { return make_float2(z.y, -z.x); }   // z * -i
__device__ __forceinline__ float2 mul_pI(float2 z) { return make_float2(-z.y, z.x); }   // z * +i
__device__ __forceinline__ __half2 f2h(float2 v) { return __float22half2_rn(v); }
__device__ __forceinline__ float2 h2f(__half2 h) { return __half22float2(h); }

// 8-point DFT, forward sign (e^{-2pi i rk/8}) — used by k_stft.
__device__ __forceinline__ void dft8(float2 (&x)[8]) {
    float2 e0 = cadd(x[0], x[4]), e1 = csub(x[0], x[4]);
    float2 e2 = cadd(x[2], x[6]), e3 = csub(x[2], x[6]);
    float2 E0 = cadd(e0, e2), E2 = csub(e0, e2);
    float2 E1 = cadd(e1, mul_nI(e3)), E3 = csub(e1, mul_nI(e3));
    float2 o0 = cadd(x[1], x[5]), o1 = csub(x[1], x[5]);
    float2 o2 = cadd(x[3], x[7]), o3 = csub(x[3], x[7]);
    float2 O0 = cadd(o0, o2), O2 = csub(o0, o2);
    float2 O1 = cadd(o1, mul_nI(o3)), O3 = csub(o1, mul_nI(o3));
    float2 W1 = make_float2(SQ2H*(O1.x + O1.y), SQ2H*(O1.y - O1.x));
    float2 W2 = mul_nI(O2);
    float2 W3 = make_float2(SQ2H*(O3.y - O3.x), -SQ2H*(O3.x + O3.y));
    x[0] = cadd(E0, O0); x[4] = csub(E0, O0);
    x[1] = cadd(E1, W1); x[5] = csub(E1, W1);
    x[2] = cadd(E2, W2); x[6] = csub(E2, W2);
    x[3] = cadd(E3, W3); x[7] = csub(E3, W3);
}

// 8-point DFT, inverse sign (e^{+2pi i rk/8}).
__device__ __forceinline__ void dft8i(float2 (&x)[8]) {
    float2 e0 = cadd(x[0], x[4]), e1 = csub(x[0], x[4]);
    float2 e2 = cadd(x[2], x[6]), e3 = csub(x[2], x[6]);
    float2 E0 = cadd(e0, e2), E2 = csub(e0, e2);
    float2 E1 = cadd(e1, mul_pI(e3)), E3 = csub(e1, mul_pI(e3));
    float2 o0 = cadd(x[1], x[5]), o1 = csub(x[1], x[5]);
    float2 o2 = cadd(x[3], x[7]), o3 = csub(x[3], x[7]);
    float2 O0 = cadd(o0, o2), O2 = csub(o0, o2);
    float2 O1 = cadd(o1, mul_pI(o3)), O3 = csub(o1, mul_pI(o3));
    float2 W1 = make_float2(SQ2H*(O1.x - O1.y), SQ2H*(O1.x + O1.y));   // *e^{+i pi/4}
    float2 W2 = mul_pI(O2);
    float2 W3 = make_float2(-SQ2H*(O3.x + O3.y), SQ2H*(O3.x - O3.y));  // *e^{+3i pi/4}
    x[0] = cadd(E0, O0); x[4] = csub(E0, O0);
    x[1] = cadd(E1, W1); x[5] = csub(E1, W1);
    x[2] = cadd(E2, W2); x[6] = csub(E2, W2);
    x[3] = cadd(E3, W3); x[7] = csub(E3, W3);
}

// 3-point DFT, inverse sign.
#define S3C 0.86602540378443865f
__device__ __forceinline__ void dft3i(float2& x0, float2& x1, float2& x2) {
    float2 u = cadd(x1, x2), v = csub(x1, x2);
    float2 w = make_float2(x0.x - 0.5f*u.x, x0.y - 0.5f*u.y);
    x0 = cadd(x0, u);
    float2 iv = make_float2(-S3C * v.y, S3C * v.x);
    x1 = cadd(w, iv);
    x2 = csub(w, iv);
}

// 5-point DFT, inverse sign.
#define C51 0.30901699437494742f
#define S51 0.95105651629515357f
#define C52 (-0.80901699437494742f)
#define S52 0.58778525229247313f
__device__ __forceinline__ void dft5i(float2& x0, float2& x1, float2& x2,
                                      float2& x3, float2& x4) {
    float2 t1 = cadd(x1, x4), t2 = csub(x1, x4);
    float2 t3 = cadd(x2, x3), t4 = csub(x2, x3);
    float2 s0 = x0;
    x0 = make_float2(s0.x + t1.x + t3.x, s0.y + t1.y + t3.y);
    float2 A1 = make_float2(s0.x + C51*t1.x + C52*t3.x, s0.y + C51*t1.y + C52*t3.y);
    float2 B1 = make_float2(S51*t2.x + S52*t4.x, S51*t2.y + S52*t4.y);
    float2 A2 = make_float2(s0.x + C52*t1.x + C51*t3.x, s0.y + C52*t1.y + C51*t3.y);
    float2 B2 = make_float2(S52*t2.x - S51*t4.x, S52*t2.y - S51*t4.y);
    x1 = make_float2(A1.x - B1.y, A1.y + B1.x);
    x4 = make_float2(A1.x + B1.y, A1.y - B1.x);
    x2 = make_float2(A2.x - B2.y, A2.y + B2.x);
    x3 = make_float2(A2.x + B2.y, A2.y - B2.x);
}

// Stage 1 (R13 configuration — best known): 16 k2 rows per block packed as 8
// complex FFT-512 (real-pair packing), TWO FFTs per wave (xa/xb gives in-thread
// ILP that beats higher occupancy — R14 A/B). Only k2 < 188 stored:
// A[375-k2] = conj(A[k2]). 1D grid 768, sig = bid&63 (XCD L2 sharing).
#define SSTR 520   // strip stride (floats); 520 % 32 == 8
__global__ void __launch_bounds__(256) k_stage1(const float* __restrict__ X0,
                                                const float* __restrict__ X1,
                                                __half2* __restrict__ A) {
    const int bid  = blockIdx.x;       // [0,768)
    const int sig  = bid & 63;
    const int kb   = bid >> 6;         // [0,12)
    const int base = kb * 16;
    const float* X = (sig < 32) ? (X0 + (size_t)sig * NROW)
                                : (X1 + (size_t)(sig - 32) * NROW);
    __shared__ float SR[8 * SSTR], SI[8 * SSTR];   // 33280 B total
    const int tid = threadIdx.x;
    const int row = tid & 7;           // complex row index
    const int ln  = tid >> 3;          // [0,32)

    const int k2e0 = base + 2 * row;
    const int k2e  = (k2e0 < NK2) ? k2e0 : (NK2 - 1);
    const int k2o  = (k2e0 + 1 < NK2) ? (k2e0 + 1) : (NK2 - 1);

    // ---- staging: z_row[n] = (X[375n + k2e], X[375n + k2o]), n = ln + 32m
    #pragma unroll
    for (int m = 0; m < 16; ++m) {
        int i = ln + 32 * m;
        int ide = 375 * i + k2e;
        int ido = 375 * i + k2o;
        float xe = X[(ide <= 96000) ? ide : (NN - ide)];
        float xo = X[(ido <= 96000) ? ido : (NN - ido)];
        SR[SSTR * row + i] = xe;
        SI[SSTR * row + i] = xo;
    }
    __syncthreads();

    // ---- per-wave FFT-512 (radix 8,8,8, inverse sign) on rows 2w, 2w+1
    const int w = tid >> 6;            // wave id
    const int l = tid & 63;            // lane
    float* sra = SR + SSTR * (2 * w);     float* sia = SI + SSTR * (2 * w);
    float* srb = SR + SSTR * (2 * w + 1); float* sib = SI + SSTR * (2 * w + 1);
    float2 xa[8], xb[8];

    // phase A: x[n1] = z[l + 64 n1]; dft8 over n1; twiddle W512^{+l*a}
    #pragma unroll
    for (int n1 = 0; n1 < 8; ++n1) {
        int ad = l + 64 * n1;
        xa[n1] = make_float2(sra[ad], sia[ad]);
        xb[n1] = make_float2(srb[ad], sib[ad]);
    }
    dft8i(xa); dft8i(xb);
    {
        float sn, cs; __sincosf(TWO_PI * (float)l * (1.0f / 512.0f), &sn, &cs);
        float2 bw = make_float2(cs, sn), tw = bw;
        xa[1] = cmul(xa[1], tw); xb[1] = cmul(xb[1], tw);
        #pragma unroll
        for (int k = 2; k < 8; ++k) {
            tw = cmul(tw, bw);
            xa[k] = cmul(xa[k], tw); xb[k] = cmul(xb[k], tw);
        }
    }
    // exchange 1 write: addr = 64a + (l ^ 8a)
    #pragma unroll
    for (int a2 = 0; a2 < 8; ++a2) {
        int ad = 64 * a2 + (l ^ (8 * a2));
        sra[ad] = xa[a2].x; sia[ad] = xa[a2].y;
        srb[ad] = xb[a2].x; sib[ad] = xb[a2].y;
    }
    __builtin_amdgcn_wave_barrier();   // keep reads below from hoisting above writes

    // phase B: lane = (l0 = l&7, aa = l>>3); y[l1] = T_A[l0+8l1][aa]
    const int l0 = l & 7, aa = l >> 3;
    #pragma unroll
    for (int l1 = 0; l1 < 8; ++l1) {
        int ad = 64 * aa + ((l0 + 8 * l1) ^ (8 * aa));
        xa[l1] = make_float2(sra[ad], sia[ad]);
        xb[l1] = make_float2(srb[ad], sib[ad]);
    }
    dft8i(xa); dft8i(xb);
    {
        float sn, cs; __sincosf(TWO_PI * (float)l0 * (1.0f / 64.0f), &sn, &cs);
        float2 bw = make_float2(cs, sn), tw = bw;
        xa[1] = cmul(xa[1], tw); xb[1] = cmul(xb[1], tw);
        #pragma unroll
        for (int k = 2; k < 8; ++k) {
            tw = cmul(tw, bw);
            xa[k] = cmul(xa[k], tw); xb[k] = cmul(xb[k], tw);
        }
    }
    // exchange 2 write: addr = 64b + 8aa + (l0 ^ b)
    #pragma unroll
    for (int b2 = 0; b2 < 8; ++b2) {
        int ad = 64 * b2 + 8 * aa + (l0 ^ b2);
        sra[ad] = xa[b2].x; sia[ad] = xa[b2].y;
        srb[ad] = xb[b2].x; sib[ad] = xb[b2].y;
    }
    __builtin_amdgcn_wave_barrier();

    // phase C: lane = (a3 = l&7, b3 = l>>3); w[l0] = T_B[l0][a3][b3]
    const int a3 = l & 7, b3 = l >> 3;
    #pragma unroll
    for (int l0r = 0; l0r < 8; ++l0r) {
        int ad = 64 * b3 + 8 * a3 + (l0r ^ b3);
        xa[l0r] = make_float2(sra[ad], sia[ad]);
        xb[l0r] = make_float2(srb[ad], sib[ad]);
    }
    dft8i(xa); dft8i(xb);
    // Z[a3 + 8 b3 + 64 c] — natural order for the epilogue
    #pragma unroll
    for (int c = 0; c < 8; ++c) {
        int ad = a3 + 8 * b3 + 64 * c;
        sra[ad] = xa[c].x; sia[ad] = xa[c].y;
        srb[ad] = xb[c].x; sib[ad] = xb[c].y;
    }
    __syncthreads();

    // ---- Hermitian unpack + twiddle W_N^{+k2 i} (chained) + coalesced half2 store
    if (k2e0 < NK2) {
        float sn, cs;
        __sincosf(TWO_PI * (float)(k2e * ln) * (1.0f / 192000.0f), &sn, &cs);
        float2 wke = make_float2(cs, sn);
        __sincosf(TWO_PI * (float)(32 * k2e) * (1.0f / 192000.0f), &sn, &cs);
        float2 ste = make_float2(cs, sn);
        __sincosf(TWO_PI * (float)(k2o * ln) * (1.0f / 192000.0f), &sn, &cs);
        float2 wko = make_float2(cs, sn);
        __sincosf(TWO_PI * (float)(32 * k2o) * (1.0f / 192000.0f), &sn, &cs);
        float2 sto = make_float2(cs, sn);
        const bool odd_ok = (k2e0 + 1 < NK2);
        __half2* Ae = A + ((size_t)sig * NK2 + k2e) * 512;
        __half2* Ao = A + ((size_t)sig * NK2 + k2o) * 512;
        const float* zr = SR + SSTR * row;
        const float* zi = SI + SSTR * row;
        #pragma unroll
        for (int m = 0; m < 16; ++m) {
            int k  = ln + 32 * m;
            int km = (512 - k) & 511;
            float2 Z  = make_float2(zr[k],  zi[k]);
            float2 Zm = make_float2(zr[km], zi[km]);
            float2 S = make_float2(Z.x + Zm.x, Z.y - Zm.y);    // Z + conj(Zm)
            float2 D = make_float2(Z.x - Zm.x, Z.y + Zm.y);    // Z - conj(Zm)
            float2 Xe = make_float2(0.5f * S.x, 0.5f * S.y);
            float2 Xo = make_float2(0.5f * D.y, -0.5f * D.x);  // D/(2i)
            Ae[k] = f2h(cmul(Xe, wke));
            if (odd_ok) Ao[k] = f2h(cmul(Xo, wko));
            wke = cmul(wke, ste);
            wko = cmul(wko, sto);
        }
    }
}

// Stage 2: block = (t1 tile of 32 = 16 PAIRS, sig). Two-for-one real-output
// IDFT-375: z[k2] = A[k2][t1a] + i*A[k2][t1a+1] (A column conj-symmetric =>
// each output real) -> one complex DFT yields y_a = Re, y_b = Im.
// Rows k2 >= 188 synthesized from conj symmetry. Grid (16, 64).
#define TP2 16     // pairs per block (32 t1)
#define T1STR 17
__global__ void __launch_bounds__(256) k_stage2(const __half2* __restrict__ A,
                                                __half* __restrict__ Y) {
    const int t1b = blockIdx.x * (2 * TP2);   // first t1 of tile (even)
    const int sig = blockIdx.y;
    __shared__ float SRT[375 * T1STR], SIT[375 * T1STR];  // 51000 B
    const int tid = threadIdx.x;

    if (blockIdx.x == 0) {             // zero pad tail Y[sig][192000:192512)
        for (int j = tid; j < 512; j += 256)
            Y[(size_t)sig * LP + NN + j] = __float2half(0.f);
    }

    // Phase A: per (c<25, pair): DFT-15 over a (k2 = 25a + c) + twiddle W375^{ce}
    for (int w = tid; w < 25 * TP2; w += 256) {
        int c = w >> 4, pl = w & 15;            // pair lane
        float2 v[15];
        const float2* Asf = (const float2*)(A + (size_t)sig * (NK2 * 512) + t1b + 2 * pl);
        #pragma unroll
        for (int a = 0; a < 15; ++a) {
            int k2 = 25 * a + c;
            if (k2 < NK2) {
                float2 raw = Asf[(size_t)k2 * 256];
                float2 fa = h2f(((const __half2*)&raw)[0]);
                float2 fb = h2f(((const __half2*)&raw)[1]);
                v[a] = make_float2(fa.x - fb.y, fa.y + fb.x);       // A_a + i A_b
            } else {
                float2 raw = Asf[(size_t)(375 - k2) * 256];
                float2 fa = h2f(((const __half2*)&raw)[0]);
                float2 fb = h2f(((const __half2*)&raw)[1]);
                v[a] = make_float2(fa.x + fb.y, fb.x - fa.y);       // conj(u_a)+i conj(u_b)
            }
        }
        #pragma unroll
        for (int r = 0; r < 5; ++r) dft3i(v[r], v[r + 5], v[r + 10]);
        float2 tw[15];
        tw[0] = make_float2(1.f, 0.f);
        float sn, cs; __sincosf(TWO_PI * (float)c * (1.0f / 375.0f), &sn, &cs);
        float2 stp = make_float2(cs, sn);
        #pragma unroll
        for (int e = 1; e < 15; ++e) tw[e] = cmul(tw[e - 1], stp);
        #pragma unroll
        for (int e3 = 0; e3 < 3; ++e3) {
            float2 h0 = v[5 * e3], h1, h2, h3, h4;
            if (e3 == 0) { h1 = v[1]; h2 = v[2]; h3 = v[3]; h4 = v[4]; }
            else if (e3 == 1) {
                h1 = cmul(v[6],  make_float2(0.91354545764260090f, 0.40673664307580021f));   // W15^1
                h2 = cmul(v[7],  make_float2(0.66913060635885821f, 0.74314482547739424f));   // W15^2
                h3 = cmul(v[8],  make_float2(0.30901699437494742f, 0.95105651629515357f));   // W15^3
                h4 = cmul(v[9],  make_float2(-0.10452846326765347f, 0.99452189536827334f));  // W15^4
            } else {
                h1 = cmul(v[11], make_float2(0.66913060635885821f, 0.74314482547739424f));   // W15^2
                h2 = cmul(v[12], make_float2(-0.10452846326765347f, 0.99452189536827334f));  // W15^4
                h3 = cmul(v[13], make_float2(-0.80901699437494742f, 0.58778525229247313f));  // W15^6
                h4 = cmul(v[14], make_float2(-0.97814760073380564f, -0.20791169081775934f)); // W15^8
            }
            dft5i(h0, h1, h2, h3, h4);
            float2 o0 = cmul(h0, tw[e3]);
            float2 o1 = cmul(h1, tw[e3 + 3]);
            float2 o2 = cmul(h2, tw[e3 + 6]);
            float2 o3 = cmul(h3, tw[e3 + 9]);
            float2 o4 = cmul(h4, tw[e3 + 12]);
            int r0 = ((e3     ) * 25 + c) * T1STR + pl;
            int r1 = ((e3 + 3 ) * 25 + c) * T1STR + pl;
            int r2 = ((e3 + 6 ) * 25 + c) * T1STR + pl;
            int r3 = ((e3 + 9 ) * 25 + c) * T1STR + pl;
            int r4 = ((e3 + 12) * 25 + c) * T1STR + pl;
            SRT[r0] = o0.x; SIT[r0] = o0.y;
            SRT[r1] = o1.x; SIT[r1] = o1.y;
            SRT[r2] = o2.x; SIT[r2] = o2.y;
            SRT[r3] = o3.x; SIT[r3] = o3.y;
            SRT[r4] = o4.x; SIT[r4] = o4.y;
        }
    }
    __syncthreads();

    // Phase B: per (e<15, pair): DFT-25 over c = 5*c1 + c2, all-constant twiddles
    if (tid < 15 * TP2) {
        int e = tid >> 4, pl = tid & 15;
        float2 t[25];
        #pragma unroll
        for (int c = 0; c < 25; ++c) {
            int rr = (e * 25 + c) * T1STR + pl;
            t[c] = make_float2(SRT[rr], SIT[rr]);
        }
        #pragma unroll
        for (int c2 = 0; c2 < 5; ++c2)
            dft5i(t[c2], t[c2 + 5], t[c2 + 10], t[c2 + 15], t[c2 + 20]);
        t[6]  = cmul(t[6],  make_float2(0.96858316112863108f, 0.24868988716485479f));   // W25^1
        t[11] = cmul(t[11], make_float2(0.87630668004386358f, 0.48175367410171532f));   // W25^2
        t[16] = cmul(t[16], make_float2(0.72896862742141155f, 0.68454710592868873f));   // W25^3
        t[21] = cmul(t[21], make_float2(0.53582679497899666f, 0.84432792550201508f));   // W25^4
        t[7]  = cmul(t[7],  make_float2(0.87630668004386358f, 0.48175367410171532f));   // W25^2
        t[12] = cmul(t[12], make_float2(0.53582679497899666f, 0.84432792550201508f));   // W25^4
        t[17] = cmul(t[17], make_float2(0.06279051952931337f, 0.99802672842827156f));   // W25^6
        t[22] = cmul(t[22], make_float2(-0.42577929156507272f, 0.90482705246601958f));  // W25^8
        t[8]  = cmul(t[8],  make_float2(0.72896862742141155f, 0.68454710592868873f));   // W25^3
        t[13] = cmul(t[13], make_float2(0.06279051952931337f, 0.99802672842827156f));   // W25^6
        t[18] = cmul(t[18], make_float2(-0.63742398974868975f, 0.77051324277578925f));  // W25^9
        t[23] = cmul(t[23], make_float2(-0.99211470131447788f, 0.12533323356430426f));  // W25^12
        t[9]  = cmul(t[9],  make_float2(0.53582679497899666f, 0.84432792550201508f));   // W25^4
        t[14] = cmul(t[14], make_float2(-0.42577929156507272f, 0.90482705246601958f));  // W25^8
        t[19] = cmul(t[19], make_float2(-0.99211470131447788f, 0.12533323356430426f));  // W25^12
        t[24] = cmul(t[24], make_float2(-0.63742398974868997f, -0.77051324277578903f)); // W25^16
        #pragma unroll
        for (int u5 = 0; u5 < 5; ++u5)
            dft5i(t[5*u5], t[5*u5 + 1], t[5*u5 + 2], t[5*u5 + 3], t[5*u5 + 4]);
        // w[t2] -> y_a = Re, y_b = Im; paired half2 store at (t1a, t1a+1)
        __half2* yb2 = (__half2*)(Y + (size_t)sig * LP + t1b + 2 * pl);
        #pragma unroll
        for (int u5 = 0; u5 < 5; ++u5)
            #pragma unroll
            for (int u5p = 0; u5p < 5; ++u5p) {
                int d = u5 + 5 * u5p;          // t2 = 15*d + e
                float2 wv = t[5 * u5 + u5p];
                yb2[(size_t)256 * (15 * d + e)] =
                    __floats2half2_rn(wv.x * (1.0f / 192000.0f),
                                      wv.y * (1.0f / 192000.0f));
            }
    }
}

// STFT: real-packed FFT-2048 in registers (radix 8,8,8,4), 3 LDS exchanges,
// Hermitian unpack; stores |S| as half (P stride 2050). 1D grid 5952,
// sig = bid&63 -> same-signal frames share one XCD L2 (window overlap reuse).
__global__ void __launch_bounds__(256) k_stft(const __half* __restrict__ Y,
                                              __half* __restrict__ P,
                                              float* __restrict__ ACC) {
    const int bid = blockIdx.x;
    const int sig = bid & 63;     // [0,64)
    const int fr  = bid >> 6;     // [0,93)
    const int lt  = threadIdx.x;  // [0,256)
    __shared__ float SR[2560], SI[2560];
    __shared__ float2 wt2[32];
    float2 x[8];
    float2 base2048;              // e^{+i*2pi*lt/2048}

    if (bid == 0 && lt < 64) ACC[lt] = 0.f;   // zero loss accumulators

    {
        const __half2* yb = (const __half2*)(Y + (size_t)sig * LP + (size_t)fr * 2048);
        float sn, cs;
        __sincosf(TWO_PI * (float)lt * (1.0f / 2048.0f), &sn, &cs);
        base2048 = make_float2(cs, sn);
        float2 ce = base2048;
        const float2 d1 = make_float2(0.99999882345170188f,   // e^{+i*pi/2048}
                                      0.00153398018628477f);
        float2 co = cmul(ce, d1);
        const float2 r45 = make_float2(SQ2H, SQ2H);
        #pragma unroll
        for (int r = 0; r < 8; ++r) {
            float2 v = h2f(yb[lt + 256 * r]);
            float we = 0.5f - 0.5f * ce.x;
            float wo = 0.5f - 0.5f * co.x;
            x[r] = make_float2(v.x * we, v.y * wo);
            ce = cmul(ce, r45);
            co = cmul(co, r45);
        }
    }
    dft8(x);
    {
        float2 b = make_float2(base2048.x, -base2048.y), tw = b;  // conj
        x[1] = cmul(x[1], tw);
        #pragma unroll
        for (int k = 2; k < 8; ++k) { tw = cmul(tw, b); x[k] = cmul(x[k], tw); }
    }
    #pragma unroll
    for (int k = 0; k < 8; ++k) { SR[k * 256 + lt] = x[k].x; SI[k * 256 + lt] = x[k].y; }
    if (lt < 32) {
        float sn, cs; __sincosf(-TWO_PI * (float)lt * (1.0f / 256.0f), &sn, &cs);
        wt2[lt] = make_float2(cs, sn);
    }
    __syncthreads();

    {
        const int k2 = lt >> 5, m1 = lt & 31;
        #pragma unroll
        for (int r = 0; r < 8; ++r) {
            int idx = k2 * 256 + m1 + 32 * r;
            x[r] = make_float2(SR[idx], SI[idx]);
        }
        dft8(x);
        float2 b = wt2[m1], tw = b;
        x[1] = cmul(x[1], tw);
        #pragma unroll
        for (int k = 2; k < 8; ++k) { tw = cmul(tw, b); x[k] = cmul(x[k], tw); }
        __syncthreads();
        #pragma unroll
        for (int j = 0; j < 8; ++j) {
            int idx = k2 * 288 + j * 36 + m1;
            SR[idx] = x[j].x; SI[idx] = x[j].y;
        }
    }
    __syncthreads();

    {
        const int k2 = lt >> 5, j2 = (lt >> 2) & 7, p1 = lt & 3;
        #pragma unroll
        for (int r = 0; r < 8; ++r) {
            int idx = k2 * 288 + j2 * 36 + p1 + 4 * r;
            x[r] = make_float2(SR[idx], SI[idx]);
        }
        dft8(x);
        float2 b = (p1 == 0) ? make_float2(1.f, 0.f)
                 : (p1 == 1) ? make_float2(0.98078528040323044f, -0.19509032201612827f)
                 : (p1 == 2) ? make_float2(0.92387953251128676f, -0.38268343236508977f)
                 :             make_float2(0.83146961230254524f, -0.55557023301960222f);
        float2 tw = b;
        x[1] = cmul(x[1], tw);
        #pragma unroll
        for (int k = 2; k < 8; ++k) { tw = cmul(tw, b); x[k] = cmul(x[k], tw); }
        __syncthreads();
        #pragma unroll
        for (int q = 0; q < 8; ++q) {
            int idx = 5 * (q * 64 + k2 * 8 + j2) + p1;
            SR[idx] = x[q].x; SI[idx] = x[q].y;
        }
    }
    __syncthreads();

    {
        float2 za[4], zb[4];
        #pragma unroll
        for (int p = 0; p < 4; ++p) {
            int ia = 5 * lt + p;
            za[p] = make_float2(SR[ia], SI[ia]);
            zb[p] = make_float2(SR[ia + 1280], SI[ia + 1280]);
        }
        __syncthreads();
        const int q2a = lt >> 6, k2 = (lt >> 3) & 7, j2 = lt & 7;
        const int kbase = k2 + 8 * j2;
        {
            float2 s0 = cadd(za[0], za[2]), s1 = csub(za[0], za[2]);
            float2 s2 = cadd(za[1], za[3]), s3 = csub(za[1], za[3]);
            float2 X0 = cadd(s0, s2), X2 = csub(s0, s2);
            float2 X1 = cadd(s1, mul_nI(s3)), X3 = csub(s1, mul_nI(s3));
            int ka = kbase + 64 * q2a;
            SR[ka]        = X0.x; SI[ka]        = X0.y;
            SR[ka + 512]  = X1.x; SI[ka + 512]  = X1.y;
            SR[ka + 1024] = X2.x; SI[ka + 1024] = X2.y;
            SR[ka + 1536] = X3.x; SI[ka + 1536] = X3.y;
        }
        {
            float2 s0 = cadd(zb[0], zb[2]), s1 = csub(zb[0], zb[2]);
            float2 s2 = cadd(zb[1], zb[3]), s3 = csub(zb[1], zb[3]);
            float2 X0 = cadd(s0, s2), X2 = csub(s0, s2);
            float2 X1 = cadd(s1, mul_nI(s3)), X3 = csub(s1, mul_nI(s3));
            int kb = kbase + 64 * (q2a + 4);
            SR[kb]        = X0.x; SI[kb]        = X0.y;
            SR[kb + 512]  = X1.x; SI[kb + 512]  = X1.y;
            SR[kb + 1024] = X2.x; SI[kb + 1024] = X2.y;
            SR[kb + 1536] = X3.x; SI[kb + 1536] = X3.y;
        }
    }
    __syncthreads();

    {
        __half* pb = P + (size_t)sig * PTS + (size_t)fr * PSTR;
        // wk = e^{-i*2pi*lt/4096} via half-angle of base2048 (lt<256 -> theta<0.79)
        float c2 = sqrtf(0.5f * (1.f + base2048.x));
        float s2 = sqrtf(0.5f * (1.f - base2048.x));
        float2 wk = make_float2(c2, -s2);
        const float2 stp = make_float2(0.92387953251128676f,   // e^{-i*pi/8}
                                       -0.38268343236508977f);
        #pragma unroll
        for (int j = 0; j < 8; ++j) {
            int k  = lt + 256 * j;
            int kc = (2048 - k) & 2047;
            float zr = SR[k],  zi = SI[k];
            float cr = SR[kc], ci = SI[kc];
            float Ex = 0.5f * (zr + cr), Ey = 0.5f * (zi - ci);
            float Ox = 0.5f * (zi + ci), Oy = -0.5f * (zr - cr);
            float Xx = Ex + wk.x * Ox - wk.y * Oy;
            float Xy = Ey + wk.x * Oy + wk.y * Ox;
            pb[k] = __float2half_rn(sqrtf(Xx * Xx + Xy * Xy));   // store |S|
            wk = cmul(wk, stp);
        }
        if (lt == 0) { float d0 = SR[0] - SI[0]; pb[2048] = __float2half_rn(fabsf(d0)); }
    }
}

// EDR + loss partials. P holds |S| as half; square on load.
// 1 bin per thread, grid (9,32); dB via hardware v_log_f32.
__global__ void __launch_bounds__(256) k_edr(const __half* __restrict__ P,
                                             float* __restrict__ ACC) {
    const int b = blockIdx.y;
    const int f = blockIdx.x * 256 + threadIdx.x;
    const bool act = (f < NF);
    const __half* Pt = P + (size_t)b * PTS;
    const __half* Pa = P + (size_t)(b + 32) * PTS;
    float st = 0.f, sa = 0.f, num = 0.f, den = 0.f;
    if (act) {
        for (int t = NT - 1; t >= 0; --t) {
            float vt = __half2float(Pt[(size_t)t * PSTR + f]);
            float va = __half2float(Pa[(size_t)t * PSTR + f]);
            st += vt * vt;
            sa += va * va;
            float et = DB_LOG2 * __log2f(st);
            float ea = DB_LOG2 * __log2f(sa);
            num += fabsf(et - ea);
            den += fabsf(et);
        }
    }
    for (int off = 32; off > 0; off >>= 1) {
        num += __shfl_down(num, off);
        den += __shfl_down(den, off);
    }
    __shared__ float sn_[4], sd_[4];
    int wave = threadIdx.x >> 6, lane = threadIdx.x & 63;
    if (lane == 0) { sn_[wave] = num; sd_[wave] = den; }
    __syncthreads();
    if (threadIdx.x == 0) {
        float n = sn_[0] + sn_[1] + sn_[2] + sn_[3];
        float d = sd_[0] + sd_[1] + sd_[2] + sd_[3];
        atomicAdd(&ACC[2 * b], n);
        atomicAdd(&ACC[2 * b + 1], d);
    }
}

__global__ void k_final(const float* __restrict__ ACC, float* __restrict__ out) {
    int tid = threadIdx.x;
    float r = 0.f;
    if (tid < 32) r = ACC[2 * tid] / ACC[2 * tid + 1];
    for (int off = 32; off > 0; off >>= 1) r += __shfl_down(r, off);
    if (tid == 0) out[0] = r;
}

extern "C" void kernel_launch(void* const* d_in, const int* in_sizes, int n_in,
                              void* d_out, int out_size, void* d_ws, size_t ws_size,
                              hipStream_t stream) {
    const float* X0 = (const float*)d_in[0];
    const float* X1 = (const float*)d_in[1];
    float* out = (float*)d_out;

    char* base = (char*)d_ws;
    __half*  P  = (__half*)(base + WS_P_OFF);
    __half2* A  = (__half2*)(base + WS_A_OFF);
    __half*  Y  = (__half*)(base + WS_Y_OFF);
    float*   ACC = (float*)(base + WS_ACC_OFF);

    k_stage1<<<dim3(768),      dim3(256), 0, stream>>>(X0, X1, A);
    k_stage2<<<dim3(16, 64),   dim3(256), 0, stream>>>(A, Y);
    k_stft  <<<dim3(5952),     dim3(256), 0, stream>>>(Y, P, ACC);
    k_edr   <<<dim3(9, 32),    dim3(256), 0, stream>>>(P, ACC);
    k_final <<<1, 64, 0, stream>>>(ACC, out);
}